// Round 11
// baseline (215.680 us; speedup 1.0000x reference)
//
#include <hip/hip_runtime.h>
#include <math.h>

#define ALPHA_SLOPE 0.2f

typedef _Float16 f16;
typedef f16 f16x4 __attribute__((ext_vector_type(4)));
typedef f16 f16x8 __attribute__((ext_vector_type(8)));
typedef float f32x4 __attribute__((ext_vector_type(4)));

constexpr int B_ = 8, N = 2048, D = 128, H = 2;
constexpr int C2 = H * D;           // 256
constexpr int M_ = B_ * N;          // 16384
constexpr int NCH = 32;             // scan chunks
constexpr int CHL = N / NCH;        // 64

__device__ __forceinline__ float lrelu(float x) { return fmaxf(x, ALPHA_SLOPE * x); }

// ---------- cvt: W -> WcT f16 (both layers), 128 blocks ----------
__global__ __launch_bounds__(256) void cvt_w_kernel(
    const float* __restrict__ W00, const float* __restrict__ W01,
    const float* __restrict__ W10, const float* __restrict__ W11,
    f16* __restrict__ WcT)
{
    const int t = threadIdx.x;
    const int w = blockIdx.x;                  // [0,128)
#pragma unroll
    for (int p = 0; p < 4; ++p) {
        const int pair = w * 4 + p;            // [0,512)
        const int layer = pair >> 8, c = pair & 255;
        const float* __restrict__ W0 = layer ? W10 : W00;
        const float* __restrict__ W1 = layer ? W11 : W01;
        const float v = (c < D) ? W0[t * D + c] : W1[t * D + (c - D)];
        WcT[(size_t)layer * C2 * C2 + c * C2 + t] = (f16)v;
    }
}

// ---------- gemm_lr: 32-row tiles, MFMA, f16 h store, l/r from LDS tile ----------
// layer 0 stages fp32 x (inline convert); layer 1 stages f16 xh.
__global__ __launch_bounds__(256) void gemm_lr_kernel(
    const float* __restrict__ xf32, const f16* __restrict__ xh, const int use_f32,
    const f16* __restrict__ Wl,
    const float* __restrict__ b0, const float* __restrict__ b1,
    const float* __restrict__ a0, const float* __restrict__ a1,
    f16* __restrict__ h,
    float* __restrict__ l0, float* __restrict__ r0,
    float* __restrict__ l1, float* __restrict__ r1)
{
    __shared__ f16 hts[32][C2 + 8];   // 16896 B: x tile, then h tile
    const int t = threadIdx.x;
    const int row0 = blockIdx.x * 32;
    if (use_f32) {
#pragma unroll
        for (int p = 0; p < 4; ++p) {
            const int q = p * 256 + t;
            const int row = q >> 5, cc = q & 31;
            const float* src = &xf32[(size_t)(row0 + row) * C2 + cc * 8];
            const float4 v0 = *(const float4*)&src[0];
            const float4 v1 = *(const float4*)&src[4];
            f16x8 o;
            o[0] = (f16)v0.x; o[1] = (f16)v0.y; o[2] = (f16)v0.z; o[3] = (f16)v0.w;
            o[4] = (f16)v1.x; o[5] = (f16)v1.y; o[6] = (f16)v1.z; o[7] = (f16)v1.w;
            *(f16x8*)&hts[row][cc * 8] = o;
        }
    } else {
#pragma unroll
        for (int p = 0; p < 4; ++p) {
            const int q = p * 256 + t;
            const int row = q >> 5, cc = q & 31;
            *(f16x8*)&hts[row][cc * 8] = *(const f16x8*)&xh[(size_t)(row0 + row) * C2 + cc * 8];
        }
    }
    __syncthreads();
    const int w = t >> 6, l = t & 63;
    const int fm = l & 15, fk = (l >> 4) * 8;
    f32x4 acc[2][4] = {};
#pragma unroll
    for (int ks = 0; ks < 8; ++ks) {
        f16x8 af[2], bf[4];
#pragma unroll
        for (int rt = 0; rt < 2; ++rt)
            af[rt] = *(const f16x8*)&hts[rt * 16 + fm][ks * 32 + fk];
#pragma unroll
        for (int ct = 0; ct < 4; ++ct) {
            const int col = w * 64 + ct * 16 + fm;
            bf[ct] = *(const f16x8*)&Wl[(size_t)col * C2 + ks * 32 + fk];
        }
#pragma unroll
        for (int rt = 0; rt < 2; ++rt)
#pragma unroll
            for (int ct = 0; ct < 4; ++ct)
                acc[rt][ct] = __builtin_amdgcn_mfma_f32_16x16x32_f16(af[rt], bf[ct], acc[rt][ct], 0, 0, 0);
    }
    __syncthreads();   // x reads done; reuse as h tile (f16)
#pragma unroll
    for (int rt = 0; rt < 2; ++rt)
#pragma unroll
        for (int ct = 0; ct < 4; ++ct) {
            const int col = w * 64 + ct * 16 + fm;
            const float bias = (col < D) ? b0[col] : b1[col - D];
#pragma unroll
            for (int q = 0; q < 4; ++q) {
                const int row = rt * 16 + (l >> 4) * 4 + q;
                hts[row][col] = (f16)(acc[rt][ct][q] + bias);
            }
        }
    __syncthreads();
#pragma unroll
    for (int p = 0; p < 4; ++p) {
        const int q = p * 256 + t;
        const int row = q >> 5, cc = q & 31;
        *(f16x8*)&h[(size_t)(row0 + row) * C2 + cc * 8] = *(const f16x8*)&hts[row][cc * 8];
    }
    // l/r: 8 threads per row (oct), rotated cols to dodge bank conflicts
    const int lrow = t >> 3;
    const int oct = t & 7;
    const float* __restrict__ ab = (oct >= 4) ? a1 : a0;
    float lv = 0.f, rv = 0.f;
#pragma unroll
    for (int c4 = 0; c4 < 8; ++c4) {
        const int cc = (c4 + oct) & 7;
        const int col = oct * 32 + cc * 4;
        const int cih = (oct & 3) * 32 + cc * 4;
        const f16x4 hf = *(const f16x4*)&hts[lrow][col];
        const float4 alv = *(const float4*)&ab[cih];
        const float4 arv = *(const float4*)&ab[128 + cih];
        const float h0 = (float)hf[0], h1 = (float)hf[1], h2 = (float)hf[2], h3 = (float)hf[3];
        lv += h0 * alv.x + h1 * alv.y + h2 * alv.z + h3 * alv.w;
        rv += h0 * arv.x + h1 * arv.y + h2 * arv.z + h3 * arv.w;
    }
    lv += __shfl_xor(lv, 1, 64); lv += __shfl_xor(lv, 2, 64);
    rv += __shfl_xor(rv, 1, 64); rv += __shfl_xor(rv, 2, 64);
    const int grow = row0 + lrow;
    if (oct == 0) { l0[grow] = lv; r0[grow] = rv; }
    else if (oct == 4) { l1[grow] = lv; r1[grow] = rv; }
}

// ---------- rank: 4-way j-split, 32 blocks/bh x 64 elems, + k_i count ----------
__global__ __launch_bounds__(256) void rank_kernel(
    const float* __restrict__ r0, const float* __restrict__ r1,
    const float* __restrict__ l0, const float* __restrict__ l1,
    float* __restrict__ rs_s, int* __restrict__ perm, int* __restrict__ kout)
{
    const int bh = blockIdx.y;
    const float* __restrict__ r = ((bh & 1) ? r1 : r0) + (size_t)(bh >> 1) * N;
    const float* __restrict__ lp = ((bh & 1) ? l1 : l0) + (size_t)(bh >> 1) * N;
    __shared__ float rl[N];
    __shared__ int scnt[4][64], sk2[4][64];
    const int t = threadIdx.x;
    for (int j = t; j < N; j += 256) rl[j] = r[j];
    __syncthreads();
    const int el = t & 63;
    const int q = t >> 6;
    const int e = blockIdx.x * 64 + el;
    const float re = rl[e];
    const float thr = -lp[e];
    const int qm = blockIdx.x >> 3;
    int cnt = 0, k2 = 0;
    const int jlo = q * 512, jhi = jlo + 512;
    if (q < qm) {
        for (int j = jlo; j < jhi; j += 4) {
            const float4 v = *(const float4*)&rl[j];
            cnt += (v.x >= re) + (v.y >= re) + (v.z >= re) + (v.w >= re);
            k2  += (v.x >= thr) + (v.y >= thr) + (v.z >= thr) + (v.w >= thr);
        }
    } else if (q > qm) {
        for (int j = jlo; j < jhi; j += 4) {
            const float4 v = *(const float4*)&rl[j];
            cnt += (v.x > re) + (v.y > re) + (v.z > re) + (v.w > re);
            k2  += (v.x >= thr) + (v.y >= thr) + (v.z >= thr) + (v.w >= thr);
        }
    } else {
        for (int j = jlo; j < jhi; j += 4) {
            const float4 v = *(const float4*)&rl[j];
            cnt += (v.x > re) || (v.x == re && (j + 0) < e);
            cnt += (v.y > re) || (v.y == re && (j + 1) < e);
            cnt += (v.z > re) || (v.z == re && (j + 2) < e);
            cnt += (v.w > re) || (v.w == re && (j + 3) < e);
            k2  += (v.x >= thr) + (v.y >= thr) + (v.z >= thr) + (v.w >= thr);
        }
    }
    scnt[q][el] = cnt; sk2[q][el] = k2;
    __syncthreads();
    if (t < 64) {
        const int c = scnt[0][t] + scnt[1][t] + scnt[2][t] + scnt[3][t];
        const int kk = sk2[0][t] + sk2[1][t] + sk2[2][t] + sk2[3][t];
        const int eg = blockIdx.x * 64 + t;
        const size_t g = (size_t)bh * N;
        rs_s[g + c] = rl[eg];
        perm[g + c] = eg;
        kout[g + eg] = kk;
    }
}

// ---------- scanA: per-chunk weights + local scalar scans + vector scans + totals ----------
__global__ __launch_bounds__(256) void scanA_kernel(
    const f16* __restrict__ h, const int* __restrict__ perm,
    const float* __restrict__ rs_s,
    f16* __restrict__ PA, f16* __restrict__ PB,
    float* __restrict__ SAloc, float* __restrict__ SBloc,
    float* __restrict__ totA, float* __restrict__ totB,
    float* __restrict__ stA, float* __restrict__ stB)
{
    __shared__ f16 hs[CHL][D];          // 16384 B
    __shared__ int pj[CHL];
    __shared__ float wA[CHL], wB[CHL];
    __shared__ float buf[2 * CHL];
    const int chunk = blockIdx.x, bh = blockIdx.y;
    const int b = bh >> 1, head = bh & 1;
    const int t = threadIdx.x;
    const size_t g = (size_t)bh * N + chunk * CHL;
    const float c1 = rs_s[(size_t)bh * N];
    if (t < CHL) {
        pj[t] = perm[g + t];
        const float rr = rs_s[g + t];
        const float eA = __expf(rr - c1);
        const float eB = __expf(0.2f * (rr - c1));
        wA[t] = eA; wB[t] = eB;
        buf[t] = eA;
    } else if (t < 2 * CHL) {
        const float rr = rs_s[g + (CHL - 1 - (t - CHL))];
        buf[t] = __expf(0.2f * (rr - c1));   // reversed B: suffix via prefix
    }
    __syncthreads();
    const int li = t & (CHL - 1);
#pragma unroll
    for (int off = 1; off < CHL; off <<= 1) {
        const float v = (t < 2 * CHL && li >= off) ? buf[t - off] : 0.f;
        __syncthreads();
        if (t < 2 * CHL && li >= off) buf[t] += v;
        __syncthreads();
    }
    if (t < CHL) SAloc[g + t] = buf[t];
    else if (t < 2 * CHL) SBloc[g + (CHL - 1 - li)] = buf[t];
    if (t == CHL - 1) stA[bh * NCH + chunk] = buf[CHL - 1];
    if (t == 2 * CHL - 1) stB[bh * NCH + chunk] = buf[2 * CHL - 1];
    // gather permuted h rows (f16)
#pragma unroll
    for (int p = 0; p < 4; ++p) {
        const int q = p * 256 + t;
        const int row = q >> 4, c8 = q & 15;
        const f16* src = h + (size_t)(b * N + pj[row]) * C2 + head * D;
        *(f16x8*)&hs[row][c8 * 8] = *(const f16x8*)&src[c8 * 8];
    }
    __syncthreads();
    if (t < D) {
        const int d = t;
        float acc = 0.f;
        for (int j = 0; j < CHL; ++j) {
            acc = fmaf(wA[j], (float)hs[j][d], acc);
            PA[(g + j) * D + d] = (f16)acc;
        }
        totA[(size_t)(bh * NCH + chunk) * D + d] = acc;
    } else {
        const int d = t - D;
        float acc = 0.f;
        for (int jj = 0; jj < CHL; ++jj) {
            const int j = CHL - 1 - jj;
            acc = fmaf(wB[j], (float)hs[j][d], acc);
            PB[(g + j) * D + d] = (f16)acc;
        }
        totB[(size_t)(bh * NCH + chunk) * D + d] = acc;
    }
}

// ---------- out: 128 rows/block (preamble amortized 8x), scanB folded ----------
__global__ __launch_bounds__(256) void out_kernel(
    const f16* __restrict__ h,
    const float* __restrict__ l0v, const float* __restrict__ l1v,
    const float* __restrict__ r0v, const float* __restrict__ r1v,
    const int* __restrict__ perm, const float* __restrict__ rs_s,
    const int* __restrict__ kout,
    const float* __restrict__ SAloc, const float* __restrict__ SBloc,
    const float* __restrict__ stA, const float* __restrict__ stB,
    const float* __restrict__ totA, const float* __restrict__ totB,
    const f16* __restrict__ PA, const f16* __restrict__ PB,
    float* __restrict__ out_f32, f16* __restrict__ out_f16, const int final_layer)
{
    __shared__ float ldsA[NCH][D];      // 16384 B -> exclusive prefix AOff
    __shared__ float ldsB[NCH][D];      // 16384 B -> exclusive suffix BOffS
    __shared__ float lsA[NCH], lsB[NCH];
    const int head = blockIdx.y, b = blockIdx.z;
    const int bh = b * H + head;
    const float* __restrict__ lv = (head ? l1v : l0v) + (size_t)b * N;
    const float* __restrict__ rv = (head ? r1v : r0v) + (size_t)b * N;
    const int t = threadIdx.x;
    const size_t gb = (size_t)bh * N;

    // ---- preamble: load totals, exclusive scans (once per 128 rows) ----
#pragma unroll
    for (int p = 0; p < 4; ++p) {
        const int idx = p * 256 + t;                 // [0,1024) float4 units
        const int ch = idx >> 5, c4 = idx & 31;
        *(float4*)&ldsA[ch][c4 * 4] = *(const float4*)&totA[(size_t)(bh * NCH + ch) * D + c4 * 4];
        *(float4*)&ldsB[ch][c4 * 4] = *(const float4*)&totB[(size_t)(bh * NCH + ch) * D + c4 * 4];
    }
    if (t < NCH) lsA[t] = stA[bh * NCH + t];
    else if (t < 2 * NCH) lsB[t - NCH] = stB[bh * NCH + (t - NCH)];
    __syncthreads();
    if (t < D) {
        const int d = t;
        float acc = 0.f;
        for (int q = 0; q < NCH; ++q) {
            const float tmp = ldsA[q][d];
            ldsA[q][d] = acc;
            acc += tmp;
        }
    } else {
        const int d = t - D;
        float acc = 0.f;
        for (int q = NCH - 1; q >= 0; --q) {
            const float tmp = ldsB[q][d];
            ldsB[q][d] = acc;
            acc += tmp;
        }
    }
    if (t == 0) {
        float a = 0.f;
        for (int q = 0; q < NCH; ++q) { const float tmp = lsA[q]; lsA[q] = a; a += tmp; }
    } else if (t == 1) {
        float a = 0.f;
        for (int q = NCH - 1; q >= 0; --q) { const float tmp = lsB[q]; lsB[q] = a; a += tmp; }
    }
    __syncthreads();

    const float rmx1 = rs_s[gb];
    const float rmx2 = rs_s[gb + 1];
    const int rdx = perm[gb];
    const int c0 = (t & 15) * 8;

    // ---- 8 row-groups of 16 ----
#pragma unroll 2
    for (int rr = 0; rr < 8; ++rr) {
        const int i = blockIdx.x * 128 + rr * 16 + (t >> 4);
        const float li = lv[i];
        const float ri = rv[i];
        const float rmx = (i == rdx) ? rmx2 : rmx1;
        const float m = lrelu(li + rmx);
        const float alpha = __expf(li + rmx1 - m);
        const float beta = __expf(0.2f * (li + rmx1) - m);
        const float diag = __expf(lrelu(li + ri) - m);

        const int k = kout[gb + i];
        const float SAk = (k > 0) ? (lsA[(k - 1) >> 6] + SAloc[gb + k - 1]) : 0.f;
        const float SBk = (k < N) ? (lsB[k >> 6] + SBloc[gb + k]) : 0.f;
        const float Z = fmaf(alpha, SAk, beta * SBk) - diag;
        const float invZ = 1.f / Z;

        float pa[8] = {}, pb[8] = {};
        if (k > 0) {
            const int kk = k - 1, ch = kk >> 6;
            const f16x8 v = *(const f16x8*)&PA[(gb + kk) * D + c0];
#pragma unroll
            for (int q = 0; q < 8; ++q) pa[q] = (float)v[q] + ldsA[ch][c0 + q];
        }
        if (k < N) {
            const int ch = k >> 6;
            const f16x8 v = *(const f16x8*)&PB[(gb + k) * D + c0];
#pragma unroll
            for (int q = 0; q < 8; ++q) pb[q] = (float)v[q] + ldsB[ch][c0 + q];
        }

        const f16x8 hraw = *(const f16x8*)&h[(size_t)(b * N + i) * C2 + head * D + c0];
        float o[8];
#pragma unroll
        for (int q = 0; q < 8; ++q) {
            const float hv = (float)hraw[q];
            const float num = alpha * pa[q] + beta * pb[q] - diag * hv;
            float v = fmaf(num, invZ, hv);
            o[q] = v > 0.f ? v : (__expf(v) - 1.f);
        }
        const size_t oidx = (size_t)(b * N + i) * C2 + head * D + c0;
        if (final_layer) {
            *(float4*)&out_f32[oidx] = make_float4(o[0], o[1], o[2], o[3]);
            *(float4*)&out_f32[oidx + 4] = make_float4(o[4], o[5], o[6], o[7]);
        } else {
            f16x8 ov;
#pragma unroll
            for (int q = 0; q < 8; ++q) ov[q] = (f16)o[q];
            *(f16x8*)&out_f16[oidx] = ov;
        }
    }
}

extern "C" void kernel_launch(void* const* d_in, const int* in_sizes, int n_in,
                              void* d_out, int out_size, void* d_ws, size_t ws_size,
                              hipStream_t stream)
{
    float* ws = (float*)d_ws;
    size_t off = 0;
    f16* xh = (f16*)(ws + off);   off += (size_t)M_ * C2 / 2;    // layer-1 input (f16)
    f16* WcT = (f16*)(ws + off);  off += (size_t)C2 * C2;        // 2 layers f16
    f16* h = (f16*)(ws + off);    off += (size_t)M_ * C2 / 2;
    float* l0 = ws + off;         off += (size_t)B_ * N;
    float* r0 = ws + off;         off += (size_t)B_ * N;
    float* l1 = ws + off;         off += (size_t)B_ * N;
    float* r1 = ws + off;         off += (size_t)B_ * N;
    float* rs_s = ws + off;       off += (size_t)16 * N;
    int* perm = (int*)(ws + off); off += (size_t)16 * N;
    int* kout = (int*)(ws + off); off += (size_t)16 * N;
    float* SAloc = ws + off;      off += (size_t)16 * N;
    float* SBloc = ws + off;      off += (size_t)16 * N;
    f16* PA = (f16*)(ws + off);   off += (size_t)16 * N * D / 2;
    f16* PB = (f16*)(ws + off);   off += (size_t)16 * N * D / 2;
    float* totA = ws + off;       off += (size_t)16 * NCH * D;
    float* totB = ws + off;       off += (size_t)16 * NCH * D;
    float* stA = ws + off;        off += (size_t)16 * NCH;
    float* stB = ws + off;        off += (size_t)16 * NCH;

    cvt_w_kernel<<<128, 256, 0, stream>>>(
        (const float*)d_in[2], (const float*)d_in[5],
        (const float*)d_in[8], (const float*)d_in[11], WcT);

    for (int layer = 0; layer < 2; ++layer) {
        const int base = 2 + layer * 6;
        const float* b0 = (const float*)d_in[base + 1];
        const float* a0 = (const float*)d_in[base + 2];
        const float* b1 = (const float*)d_in[base + 4];
        const float* a1 = (const float*)d_in[base + 5];

        gemm_lr_kernel<<<M_ / 32, 256, 0, stream>>>(
            (const float*)d_in[0], xh, layer == 0 ? 1 : 0,
            WcT + (size_t)layer * C2 * C2, b0, b1, a0, a1, h, l0, r0, l1, r1);
        rank_kernel<<<dim3(N / 64, B_ * H), 256, 0, stream>>>(
            r0, r1, l0, l1, rs_s, perm, kout);
        scanA_kernel<<<dim3(NCH, B_ * H), 256, 0, stream>>>(
            h, perm, rs_s, PA, PB, SAloc, SBloc, totA, totB, stA, stB);
        out_kernel<<<dim3(N / 128, H, B_), 256, 0, stream>>>(
            h, l0, l1, r0, r1, perm, rs_s, kout, SAloc, SBloc, stA, stB,
            totA, totB, PA, PB, (float*)d_out, xh, layer == 1 ? 1 : 0);
    }
}